// Round 6
// baseline (107.349 us; speedup 1.0000x reference)
//
#include <hip/hip_runtime.h>
#include <float.h>

// Problem constants (B=16, N=M=4096, fp32, 3-D points)
#define BATCH    16
#define NPTS     4096
#define TOTALP   (BATCH * NPTS)        // 65536 points per set
#define NQ       (2 * TOTALP)          // 131072 query points (both dirs)

// ---------------------------------------------------------------------------
// Partial kernel. Q=8 queries/thread, opposite chunk staged in LDS.
//   blk = (((dir*16 + b)*2 + qg)*CHUNKS + c       (ALL selectors uniform)
//     dir in [0,2), b in [0,16) batch, qg in [0,2): group of 2048 queries,
//     c in [0,CHUNKS): chunk of the opposite set (L = NPTS/CHUNKS points).
//   Staging: threads cooperatively read raw xyz, compute w = 0.5*||p||^2,
//   write float4 tile to LDS. Hot loop: 4 wave-uniform ds_read_b128
//   (broadcast, conflict-free) serve 4 points x 8 queries x 64 lanes = 2048
//   pairs; per query 12 fma + 2 v_min3 -> 3.5 VALU/pair.
//   t_m = w_m - x.p_m ;  partial[c][q] = min_m t_m  (d = ||x||^2 + 2*min t)
// Block 0 also zeroes d_out (poisoned 0xAA before every timed launch).
// ---------------------------------------------------------------------------
template <int CHUNKS>
__global__ __launch_bounds__(256) void chamfer_partial_lds(
    const float* __restrict__ xyz1, const float* __restrict__ xyz2,
    float* __restrict__ partial, float* __restrict__ out)
{
    constexpr int L = NPTS / CHUNKS;           // chunk length (power of 2)
    __shared__ float4 tile[L];

    const int blk = blockIdx.x;
    const int c   = blk % CHUNKS;
    const int qg  = (blk / CHUNKS) & 1;
    const int b   = (blk / (CHUNKS * 2)) & 15;
    const int dir = blk / (CHUNKS * 32);       // block-uniform

    if (blk == 0 && threadIdx.x == 0) { out[0] = 0.0f; out[1] = 0.0f; }

    // ---- stage chunk into LDS (per-lane VMEM reads) ----
    const float* __restrict__ opp =
        (dir == 0 ? xyz2 : xyz1) + (size_t)(b * NPTS + c * L) * 3;
    for (int i = threadIdx.x; i < L; i += 256) {
        const float px = opp[3 * i + 0];
        const float py = opp[3 * i + 1];
        const float pz = opp[3 * i + 2];
        tile[i] = make_float4(px, py, pz, 0.5f * (px * px + py * py + pz * pz));
    }

    // ---- load 8 query points (per-lane VMEM) ----
    const float* __restrict__ ownp =
        (dir == 0 ? xyz1 : xyz2) + (size_t)b * NPTS * 3;
    const int q0 = (qg << 11) + threadIdx.x;   // local query idx; +256*j
    float nx[8], ny[8], nz[8];
#pragma unroll
    for (int j = 0; j < 8; ++j) {
        const int qi = q0 + (j << 8);
        nx[j] = -ownp[3 * qi + 0];
        ny[j] = -ownp[3 * qi + 1];
        nz[j] = -ownp[3 * qi + 2];
    }

    __syncthreads();

    // ---- hot loop: 4 uniform ds_read_b128 + 96 fma + 16 min3 per step ----
    float acc[8];
#pragma unroll
    for (int j = 0; j < 8; ++j) acc[j] = FLT_MAX;

    for (int m = 0; m < L; m += 4) {
        float4 P[4];
#pragma unroll
        for (int u = 0; u < 4; ++u) P[u] = tile[m + u];   // broadcast reads

#pragma unroll
        for (int j = 0; j < 8; ++j) {
            float t[4];
#pragma unroll
            for (int u = 0; u < 4; ++u) {
                const float4 p = P[u];
                float s = fmaf(nz[j], p.z, p.w);
                s = fmaf(ny[j], p.y, s);
                s = fmaf(nx[j], p.x, s);
                t[u] = s;
            }
            const float a = fminf(fminf(t[0], t[1]), t[2]);   // v_min3
            acc[j] = fminf(fminf(a, t[3]), acc[j]);           // v_min3
        }
    }

    const int qbase = (dir << 16) + (b << 12) + q0;   // global query index
#pragma unroll
    for (int j = 0; j < 8; ++j)
        partial[(size_t)c * NQ + qbase + (j << 8)] = acc[j];
}

// ---------------------------------------------------------------------------
// Final kernel: 512 blocks x 256, dir block-uniform. Per query: min of
// CHUNKS partials, add ||x||^2, block-reduce sum, one atomicAdd per block.
// ---------------------------------------------------------------------------
template <int CHUNKS>
__global__ __launch_bounds__(256) void chamfer_final_kernel(
    const float* __restrict__ xyz1, const float* __restrict__ xyz2,
    const float* __restrict__ partial, float* __restrict__ out)
{
    const int dir = blockIdx.x >> 8;                       // block-uniform
    const int qi  = ((blockIdx.x & 255) << 8) + threadIdx.x;
    const int q   = (dir << 16) + qi;

    const float* __restrict__ ownp = (dir == 0 ? xyz1 : xyz2);
    const float x = ownp[3 * qi + 0];
    const float y = ownp[3 * qi + 1];
    const float z = ownp[3 * qi + 2];

    float m = partial[q];
#pragma unroll
    for (int cc = 1; cc < CHUNKS; ++cc)
        m = fminf(m, partial[(size_t)cc * NQ + q]);

    float d = (x * x + y * y + z * z) + 2.0f * m;   // = min_m ||x - p_m||^2

    for (int off = 32; off > 0; off >>= 1)
        d += __shfl_down(d, off);

    __shared__ float wsum[4];
    const int lane = threadIdx.x & 63;
    const int wv   = threadIdx.x >> 6;
    if (lane == 0) wsum[wv] = d;
    __syncthreads();
    if (threadIdx.x == 0) {
        float s = wsum[0] + wsum[1] + wsum[2] + wsum[3];
        atomicAdd(&out[dir], s * (1.0f / (float)TOTALP));
    }
}

// ---------------------------------------------------------------------------
// Fallback for tiny workspace: direct 7-op kernel, no ws needed.
// ---------------------------------------------------------------------------
__global__ void zero_out_kernel(float* __restrict__ out)
{
    if (threadIdx.x == 0) { out[0] = 0.0f; out[1] = 0.0f; }
}

__global__ __launch_bounds__(256) void chamfer_raw_kernel(
    const float* __restrict__ xyz1, const float* __restrict__ xyz2,
    float* __restrict__ out)
{
    const int blk = blockIdx.x;
    const int dir = blk >> 8;
    const int idx = blk & 255;
    const int b   = idx >> 4;
    const int n0  = (idx & 15) << 8;

    const float* __restrict__ own = (dir == 0 ? xyz1 : xyz2) + (size_t)b * NPTS * 3;
    const float* __restrict__ opp = (dir == 0 ? xyz2 : xyz1) + (size_t)b * NPTS * 3;

    const int n = n0 + threadIdx.x;
    const float ax = own[3 * n + 0];
    const float ay = own[3 * n + 1];
    const float az = own[3 * n + 2];

    float best = FLT_MAX;
    for (int m = 0; m < NPTS; m += 4) {
#pragma unroll
        for (int u = 0; u < 4; ++u) {
            const float px = opp[3 * (m + u) + 0];
            const float py = opp[3 * (m + u) + 1];
            const float pz = opp[3 * (m + u) + 2];
            const float dx = px - ax, dy = py - ay, dz = pz - az;
            float d = dx * dx;
            d = fmaf(dy, dy, d);
            d = fmaf(dz, dz, d);
            best = fminf(best, d);
        }
    }

    float d = best;
    for (int off = 32; off > 0; off >>= 1)
        d += __shfl_down(d, off);

    __shared__ float wsum[4];
    const int lane = threadIdx.x & 63;
    const int wv   = threadIdx.x >> 6;
    if (lane == 0) wsum[wv] = d;
    __syncthreads();
    if (threadIdx.x == 0) {
        float s = wsum[0] + wsum[1] + wsum[2] + wsum[3];
        atomicAdd(&out[dir], s * (1.0f / (float)TOTALP));
    }
}

// ---------------------------------------------------------------------------
extern "C" void kernel_launch(void* const* d_in, const int* in_sizes, int n_in,
                              void* d_out, int out_size, void* d_ws, size_t ws_size,
                              hipStream_t stream)
{
    const float* xyz1 = (const float*)d_in[0];
    const float* xyz2 = (const float*)d_in[1];
    float* out = (float*)d_out;
    float* partial = (float*)d_ws;

    const size_t part16 = (size_t)16 * NQ * sizeof(float);  // 8 MiB
    const size_t part8  = (size_t)8  * NQ * sizeof(float);  // 4 MiB
    const size_t part4  = (size_t)4  * NQ * sizeof(float);  // 2 MiB

    if (ws_size >= part16) {
        // 1024 blocks = 4 blocks/CU, 16 waves/CU
        chamfer_partial_lds<16><<<2 * 16 * 2 * 16, 256, 0, stream>>>(xyz1, xyz2, partial, out);
        chamfer_final_kernel<16><<<NQ / 256, 256, 0, stream>>>(xyz1, xyz2, partial, out);
    } else if (ws_size >= part8) {
        chamfer_partial_lds<8><<<2 * 16 * 2 * 8, 256, 0, stream>>>(xyz1, xyz2, partial, out);
        chamfer_final_kernel<8><<<NQ / 256, 256, 0, stream>>>(xyz1, xyz2, partial, out);
    } else if (ws_size >= part4) {
        chamfer_partial_lds<4><<<2 * 16 * 2 * 4, 256, 0, stream>>>(xyz1, xyz2, partial, out);
        chamfer_final_kernel<4><<<NQ / 256, 256, 0, stream>>>(xyz1, xyz2, partial, out);
    } else {
        zero_out_kernel<<<1, 64, 0, stream>>>(out);
        chamfer_raw_kernel<<<512, 256, 0, stream>>>(xyz1, xyz2, out);
    }
}

// Round 7
// 104.878 us; speedup vs baseline: 1.0236x; 1.0236x over previous
//
#include <hip/hip_runtime.h>
#include <float.h>

// Problem constants (B=16, N=M=4096, fp32, 3-D points)
#define BATCH    16
#define NPTS     4096
#define TOTALP   (BATCH * NPTS)        // 65536 points per set
#define NQ       (2 * TOTALP)          // 131072 query points (both dirs)
#define CHUNKS   32
#define L        (NPTS / CHUNKS)       // 128 opposite points per block

// Order-preserving float->uint encode (unsigned compare == float compare).
__device__ __forceinline__ unsigned enc(float f)
{
    unsigned b = __float_as_uint(f);
    return (b & 0x80000000u) ? ~b : (b | 0x80000000u);
}
__device__ __forceinline__ float dec(unsigned k)
{
    return (k & 0x80000000u) ? __uint_as_float(k & 0x7FFFFFFFu)
                             : __uint_as_float(~k);
}

// ---------------------------------------------------------------------------
// Partial kernel. Q=8 queries/thread, opposite chunk (L=128 pts) in LDS.
//   blk = ((dir*16 + b)*2 + qg)*32 + c          (ALL selectors block-uniform)
//     dir in [0,2), b in [0,16) batch, qg in [0,2): group of 2048 queries,
//     c in [0,32): chunk of the opposite set.
//   2048 blocks = 8 blocks/CU = 32 waves/CU (R5 evidence: DS+VALU overlap
//   needs ~32 waves/CU). Hot loop: 4 wave-uniform ds_read_b128 (broadcast,
//   conflict-free) serve 4 pts x 8 queries x 64 lanes = 2048 pairs;
//   3 fma + 0.5 v_min3 per pair = 3.5 VALU/pair.
//   t_m = 0.5||p||^2 - x.p ;  d_c = ||x||^2 + 2*min_m t_m = min ||x-p||^2
//   Merge across chunks: atomicMin on uint-encoded d (keys init 0xFF).
// ---------------------------------------------------------------------------
__global__ __launch_bounds__(256) void chamfer_partial_atomic(
    const float* __restrict__ xyz1, const float* __restrict__ xyz2,
    unsigned* __restrict__ keys)
{
    __shared__ float4 tile[L];

    const int blk = blockIdx.x;
    const int c   = blk & 31;
    const int qg  = (blk >> 5) & 1;
    const int b   = (blk >> 6) & 15;
    const int dir = blk >> 10;                  // block-uniform

    // ---- stage chunk into LDS (w = 0.5*||p||^2 fused) ----
    const float* __restrict__ opp =
        (dir == 0 ? xyz2 : xyz1) + (size_t)(b * NPTS + c * L) * 3;
    for (int i = threadIdx.x; i < L; i += 256) {
        const float px = opp[3 * i + 0];
        const float py = opp[3 * i + 1];
        const float pz = opp[3 * i + 2];
        tile[i] = make_float4(px, py, pz, 0.5f * (px * px + py * py + pz * pz));
    }

    // ---- load 8 query points (per-lane VMEM) ----
    const float* __restrict__ ownp =
        (dir == 0 ? xyz1 : xyz2) + (size_t)b * NPTS * 3;
    const int q0 = (qg << 11) + threadIdx.x;    // local query idx; +256*j
    float nx[8], ny[8], nz[8];
#pragma unroll
    for (int j = 0; j < 8; ++j) {
        const int qi = q0 + (j << 8);
        nx[j] = -ownp[3 * qi + 0];
        ny[j] = -ownp[3 * qi + 1];
        nz[j] = -ownp[3 * qi + 2];
    }

    __syncthreads();

    // ---- hot loop: 4 uniform ds_read_b128 + 96 fma + 16 min3 per step ----
    float acc[8];
#pragma unroll
    for (int j = 0; j < 8; ++j) acc[j] = FLT_MAX;

    for (int m = 0; m < L; m += 4) {
        float4 P[4];
#pragma unroll
        for (int u = 0; u < 4; ++u) P[u] = tile[m + u];   // broadcast reads

#pragma unroll
        for (int j = 0; j < 8; ++j) {
            float t[4];
#pragma unroll
            for (int u = 0; u < 4; ++u) {
                const float4 p = P[u];
                float s = fmaf(nz[j], p.z, p.w);
                s = fmaf(ny[j], p.y, s);
                s = fmaf(nx[j], p.x, s);
                t[u] = s;
            }
            const float a = fminf(fminf(t[0], t[1]), t[2]);   // v_min3
            acc[j] = fminf(fminf(a, t[3]), acc[j]);           // v_min3
        }
    }

    // ---- epilogue: d = ||x||^2 + 2*min_t, atomicMin-merge across chunks ----
    const int qbase = (dir << 16) + (b << 12) + q0;   // global query index
#pragma unroll
    for (int j = 0; j < 8; ++j) {
        const float sq = fmaf(nx[j], nx[j],
                         fmaf(ny[j], ny[j], nz[j] * nz[j]));
        const float d  = fmaf(2.0f, acc[j], sq);
        atomicMin(&keys[qbase + (j << 8)], enc(d));
    }
}

// ---------------------------------------------------------------------------
// Final kernel: 512 blocks x 256, dir block-uniform. Decode per-query min,
// block-reduce sum, one atomicAdd per block into out[dir].
// ---------------------------------------------------------------------------
__global__ __launch_bounds__(256) void chamfer_final_atomic(
    const unsigned* __restrict__ keys, float* __restrict__ out)
{
    const int dir = blockIdx.x >> 8;                       // block-uniform
    const int qi  = ((blockIdx.x & 255) << 8) + threadIdx.x;
    const int q   = (dir << 16) + qi;

    float d = dec(keys[q]);

    for (int off = 32; off > 0; off >>= 1)
        d += __shfl_down(d, off);

    __shared__ float wsum[4];
    const int lane = threadIdx.x & 63;
    const int wv   = threadIdx.x >> 6;
    if (lane == 0) wsum[wv] = d;
    __syncthreads();
    if (threadIdx.x == 0) {
        float s = wsum[0] + wsum[1] + wsum[2] + wsum[3];
        atomicAdd(&out[dir], s * (1.0f / (float)TOTALP));
    }
}

// ---------------------------------------------------------------------------
// Fallback for tiny workspace: direct 7-op kernel, no ws needed.
// ---------------------------------------------------------------------------
__global__ void zero_out_kernel(float* __restrict__ out)
{
    if (threadIdx.x == 0) { out[0] = 0.0f; out[1] = 0.0f; }
}

__global__ __launch_bounds__(256) void chamfer_raw_kernel(
    const float* __restrict__ xyz1, const float* __restrict__ xyz2,
    float* __restrict__ out)
{
    const int blk = blockIdx.x;
    const int dir = blk >> 8;
    const int idx = blk & 255;
    const int b   = idx >> 4;
    const int n0  = (idx & 15) << 8;

    const float* __restrict__ own = (dir == 0 ? xyz1 : xyz2) + (size_t)b * NPTS * 3;
    const float* __restrict__ opp = (dir == 0 ? xyz2 : xyz1) + (size_t)b * NPTS * 3;

    const int n = n0 + threadIdx.x;
    const float ax = own[3 * n + 0];
    const float ay = own[3 * n + 1];
    const float az = own[3 * n + 2];

    float best = FLT_MAX;
    for (int m = 0; m < NPTS; m += 4) {
#pragma unroll
        for (int u = 0; u < 4; ++u) {
            const float px = opp[3 * (m + u) + 0];
            const float py = opp[3 * (m + u) + 1];
            const float pz = opp[3 * (m + u) + 2];
            const float dx = px - ax, dy = py - ay, dz = pz - az;
            float d = dx * dx;
            d = fmaf(dy, dy, d);
            d = fmaf(dz, dz, d);
            best = fminf(best, d);
        }
    }

    float d = best;
    for (int off = 32; off > 0; off >>= 1)
        d += __shfl_down(d, off);

    __shared__ float wsum[4];
    const int lane = threadIdx.x & 63;
    const int wv   = threadIdx.x >> 6;
    if (lane == 0) wsum[wv] = d;
    __syncthreads();
    if (threadIdx.x == 0) {
        float s = wsum[0] + wsum[1] + wsum[2] + wsum[3];
        atomicAdd(&out[dir], s * (1.0f / (float)TOTALP));
    }
}

// ---------------------------------------------------------------------------
extern "C" void kernel_launch(void* const* d_in, const int* in_sizes, int n_in,
                              void* d_out, int out_size, void* d_ws, size_t ws_size,
                              hipStream_t stream)
{
    const float* xyz1 = (const float*)d_in[0];
    const float* xyz2 = (const float*)d_in[1];
    float* out = (float*)d_out;

    const size_t keys_bytes = (size_t)NQ * sizeof(unsigned);  // 512 KiB

    if (ws_size >= keys_bytes) {
        unsigned* keys = (unsigned*)d_ws;
        // init: keys = 0xFFFFFFFF (max), out = 0 (both async, capturable)
        hipMemsetAsync(keys, 0xFF, keys_bytes, stream);
        hipMemsetAsync(out, 0, 2 * sizeof(float), stream);
        // 2048 blocks = 8 blocks/CU = 32 waves/CU
        chamfer_partial_atomic<<<2 * 16 * 2 * CHUNKS, 256, 0, stream>>>(xyz1, xyz2, keys);
        chamfer_final_atomic<<<NQ / 256, 256, 0, stream>>>(keys, out);
    } else {
        zero_out_kernel<<<1, 64, 0, stream>>>(out);
        chamfer_raw_kernel<<<512, 256, 0, stream>>>(xyz1, xyz2, out);
    }
}

// Round 8
// 104.160 us; speedup vs baseline: 1.0306x; 1.0069x over previous
//
#include <hip/hip_runtime.h>
#include <float.h>

// Problem constants (B=16, N=M=4096, fp32, 3-D points)
#define BATCH  16
#define NPTS   4096
#define TOTALP (BATCH * NPTS)      // 65536 points per set
#define NQ     (2 * TOTALP)       // 131072 query slots (both dirs)

typedef _Float16 half8 __attribute__((ext_vector_type(8)));
typedef float    f32x4 __attribute__((ext_vector_type(4)));

// Order-preserving float->uint encode (unsigned compare == float compare).
__device__ __forceinline__ unsigned enc(float f)
{
    unsigned b = __float_as_uint(f);
    return (b & 0x80000000u) ? ~b : (b | 0x80000000u);
}
__device__ __forceinline__ float dec(unsigned k)
{
    return (k & 0x80000000u) ? __uint_as_float(k & 0x7FFFFFFFu)
                             : __uint_as_float(~k);
}

// Cross-lane min over the 16-lane row group via DPP (VALU pipe, no DS).
template <int CTRL>
__device__ __forceinline__ float dpp_min_step(float v)
{
    int o = __builtin_amdgcn_update_dpp(0, __float_as_int(v), CTRL, 0xF, 0xF, false);
    return fminf(v, __int_as_float(o));
}

union RecHalf { _Float16 h[8]; uint4 u; };

// ---------------------------------------------------------------------------
// MFMA chamfer kernel.
// d_ij = sq_i + sq_j - 2 x_i . p_j encoded ENTIRELY in one K=16 f16 dot:
//   A row i (u = -2x, hi/lo f16 split):
//     k0-7:  uxh uyh uzh uxl uyl uzl uxh uyh
//     k8-15: uzh uxl uyl uzl sh_i sl_i 1 1
//   B col j (v = p, hi/lo split):
//     k0-7:  vxh vyh vzh vxh vyh vzh vxl vyl
//     k8-15: vzl vxl vyl vzl 1 1 sh_j sl_j
//   sum_k A_k B_k = (uh+ul).(vh+vl) + sq_i + sq_j = d_ij  (err ~5e-5)
// Fragments (verified layouts, cdna_hip_programming.md S3):
//   A: m=lane&15, k=quad*8+j   -> quads 0,1 read 16B from LDS; quads 2,3 = 0
//   B: n=lane&15, k=quad*8+j   -> same pattern (k16-31 dead via zero A)
//   D: col=lane&15, row=quad*4+reg
// Block: 512 rows x 512 cols per batch/dir; 4 waves x 128 rows each.
//   blk = ((dir*16 + b)*8 + rb)*8 + cc   (ALL selectors block-uniform)
// Row-min accumulates in registers across 32 col-tiles; DPP-reduced over the
// 16 col lanes; merged globally via atomicMin on uint-encoded keys.
// ---------------------------------------------------------------------------
__global__ __launch_bounds__(256) void chamfer_mfma(
    const float* __restrict__ xyz1, const float* __restrict__ xyz2,
    unsigned* __restrict__ keys)
{
    __shared__ uint4 Astage[1024];   // 512 rows x 32B (k0-15 halves)
    __shared__ uint4 Bstage[1024];   // 512 cols x 32B

    const int blk = blockIdx.x;
    const int cc  = blk & 7;
    const int rb  = (blk >> 3) & 7;
    const int b   = (blk >> 6) & 15;
    const int dir = blk >> 10;                 // block-uniform

    const float* __restrict__ rowsrc = (dir == 0 ? xyz1 : xyz2) + (size_t)b * NPTS * 3;
    const float* __restrict__ colsrc = (dir == 0 ? xyz2 : xyz1) + (size_t)b * NPTS * 3;
    const int rowbase = rb << 9;
    const int colbase = cc << 9;
    const _Float16 one = (_Float16)1.0f;

    // ---- stage A (512 rows, 2 per thread) ----
    for (int r = threadIdx.x; r < 512; r += 256) {
        const float x = rowsrc[3 * (rowbase + r) + 0];
        const float y = rowsrc[3 * (rowbase + r) + 1];
        const float z = rowsrc[3 * (rowbase + r) + 2];
        const float ux = -2.0f * x, uy = -2.0f * y, uz = -2.0f * z;
        const _Float16 uxh = (_Float16)ux, uyh = (_Float16)uy, uzh = (_Float16)uz;
        const _Float16 uxl = (_Float16)(ux - (float)uxh);
        const _Float16 uyl = (_Float16)(uy - (float)uyh);
        const _Float16 uzl = (_Float16)(uz - (float)uzh);
        const float sq = x * x + y * y + z * z;
        const _Float16 sh = (_Float16)sq;
        const _Float16 sl = (_Float16)(sq - (float)sh);
        RecHalf r0, r1;
        r0.h[0] = uxh; r0.h[1] = uyh; r0.h[2] = uzh; r0.h[3] = uxl;
        r0.h[4] = uyl; r0.h[5] = uzl; r0.h[6] = uxh; r0.h[7] = uyh;
        r1.h[0] = uzh; r1.h[1] = uxl; r1.h[2] = uyl; r1.h[3] = uzl;
        r1.h[4] = sh;  r1.h[5] = sl;  r1.h[6] = one; r1.h[7] = one;
        Astage[2 * r]     = r0.u;
        Astage[2 * r + 1] = r1.u;
    }

    // ---- stage B (512 cols, 2 per thread) ----
    for (int c = threadIdx.x; c < 512; c += 256) {
        const float x = colsrc[3 * (colbase + c) + 0];
        const float y = colsrc[3 * (colbase + c) + 1];
        const float z = colsrc[3 * (colbase + c) + 2];
        const _Float16 vxh = (_Float16)x, vyh = (_Float16)y, vzh = (_Float16)z;
        const _Float16 vxl = (_Float16)(x - (float)vxh);
        const _Float16 vyl = (_Float16)(y - (float)vyh);
        const _Float16 vzl = (_Float16)(z - (float)vzh);
        const float sq = x * x + y * y + z * z;
        const _Float16 sh = (_Float16)sq;
        const _Float16 sl = (_Float16)(sq - (float)sh);
        RecHalf r0, r1;
        r0.h[0] = vxh; r0.h[1] = vyh; r0.h[2] = vzh; r0.h[3] = vxh;
        r0.h[4] = vyh; r0.h[5] = vzh; r0.h[6] = vxl; r0.h[7] = vyl;
        r1.h[0] = vzl; r1.h[1] = vxl; r1.h[2] = vyl; r1.h[3] = vzl;
        r1.h[4] = one; r1.h[5] = one; r1.h[6] = sh;  r1.h[7] = sl;
        Bstage[2 * c]     = r0.u;
        Bstage[2 * c + 1] = r1.u;
    }

    __syncthreads();

    const int lane = threadIdx.x & 63;
    const int wv   = threadIdx.x >> 6;
    const int n    = lane & 15;
    const int quad = lane >> 4;
    const int bq   = quad & 1;

    // ---- A fragments: 8 row-tiles (128 rows) per wave ----
    half8 afrag[8];
    if (quad < 2) {
#pragma unroll
        for (int t = 0; t < 8; ++t)
            afrag[t] = __builtin_bit_cast(
                half8, Astage[(wv * 128 + t * 16 + n) * 2 + quad]);
    } else {
        half8 z;
#pragma unroll
        for (int i = 0; i < 8; ++i) z[i] = (_Float16)0.0f;
#pragma unroll
        for (int t = 0; t < 8; ++t) afrag[t] = z;
    }

    f32x4 acc[8];
#pragma unroll
    for (int t = 0; t < 8; ++t) {
#pragma unroll
        for (int r2 = 0; r2 < 4; ++r2) acc[t][r2] = FLT_MAX;
    }

    f32x4 czero;
#pragma unroll
    for (int r2 = 0; r2 < 4; ++r2) czero[r2] = 0.0f;

    // ---- hot loop: 16 iters x (2 b128 reads + 16 MFMA + 32 min3) ----
    for (int s = 0; s < 16; ++s) {
        const half8 bf0 = __builtin_bit_cast(
            half8, Bstage[((2 * s + 0) * 16 + n) * 2 + bq]);
        const half8 bf1 = __builtin_bit_cast(
            half8, Bstage[((2 * s + 1) * 16 + n) * 2 + bq]);
#pragma unroll
        for (int t = 0; t < 8; ++t) {
            f32x4 d0 = __builtin_amdgcn_mfma_f32_16x16x32_f16(afrag[t], bf0, czero, 0, 0, 0);
            f32x4 d1 = __builtin_amdgcn_mfma_f32_16x16x32_f16(afrag[t], bf1, czero, 0, 0, 0);
#pragma unroll
            for (int r2 = 0; r2 < 4; ++r2)
                acc[t][r2] = fminf(fminf(d0[r2], d1[r2]), acc[t][r2]);   // v_min3
        }
    }

    // ---- epilogue: DPP row-reduce over 16 col lanes, atomicMin merge ----
    const unsigned kbase = ((unsigned)dir << 16) + ((unsigned)b << 12)
                         + (unsigned)rowbase + (unsigned)(wv * 128);
#pragma unroll
    for (int t = 0; t < 8; ++t) {
#pragma unroll
        for (int r2 = 0; r2 < 4; ++r2) {
            float v = acc[t][r2];
            v = dpp_min_step<0xB1>(v);    // quad_perm xor1
            v = dpp_min_step<0x4E>(v);    // quad_perm xor2
            v = dpp_min_step<0x124>(v);   // row_ror:4
            v = dpp_min_step<0x128>(v);   // row_ror:8
            if (n == 0)
                atomicMin(&keys[kbase + t * 16 + quad * 4 + r2], enc(v));
        }
    }
}

// ---------------------------------------------------------------------------
// Final kernel: 512 blocks x 256, dir block-uniform. Decode per-query min,
// block-reduce sum, one atomicAdd per block into out[dir].
// ---------------------------------------------------------------------------
__global__ __launch_bounds__(256) void chamfer_final_atomic(
    const unsigned* __restrict__ keys, float* __restrict__ out)
{
    const int dir = blockIdx.x >> 8;                       // block-uniform
    const int qi  = ((blockIdx.x & 255) << 8) + threadIdx.x;
    const int q   = (dir << 16) + qi;

    float d = dec(keys[q]);

    for (int off = 32; off > 0; off >>= 1)
        d += __shfl_down(d, off);

    __shared__ float wsum[4];
    const int lane = threadIdx.x & 63;
    const int wv   = threadIdx.x >> 6;
    if (lane == 0) wsum[wv] = d;
    __syncthreads();
    if (threadIdx.x == 0) {
        float s = wsum[0] + wsum[1] + wsum[2] + wsum[3];
        atomicAdd(&out[dir], s * (1.0f / (float)TOTALP));
    }
}

// ---------------------------------------------------------------------------
// Fallback for tiny workspace: direct 7-op kernel, no ws needed.
// ---------------------------------------------------------------------------
__global__ void zero_out_kernel(float* __restrict__ out)
{
    if (threadIdx.x == 0) { out[0] = 0.0f; out[1] = 0.0f; }
}

__global__ __launch_bounds__(256) void chamfer_raw_kernel(
    const float* __restrict__ xyz1, const float* __restrict__ xyz2,
    float* __restrict__ out)
{
    const int blk = blockIdx.x;
    const int dir = blk >> 8;
    const int idx = blk & 255;
    const int b   = idx >> 4;
    const int n0  = (idx & 15) << 8;

    const float* __restrict__ own = (dir == 0 ? xyz1 : xyz2) + (size_t)b * NPTS * 3;
    const float* __restrict__ opp = (dir == 0 ? xyz2 : xyz1) + (size_t)b * NPTS * 3;

    const int n = n0 + threadIdx.x;
    const float ax = own[3 * n + 0];
    const float ay = own[3 * n + 1];
    const float az = own[3 * n + 2];

    float best = FLT_MAX;
    for (int m = 0; m < NPTS; m += 4) {
#pragma unroll
        for (int u = 0; u < 4; ++u) {
            const float px = opp[3 * (m + u) + 0];
            const float py = opp[3 * (m + u) + 1];
            const float pz = opp[3 * (m + u) + 2];
            const float dx = px - ax, dy = py - ay, dz = pz - az;
            float d = dx * dx;
            d = fmaf(dy, dy, d);
            d = fmaf(dz, dz, d);
            best = fminf(best, d);
        }
    }

    float d = best;
    for (int off = 32; off > 0; off >>= 1)
        d += __shfl_down(d, off);

    __shared__ float wsum[4];
    const int lane = threadIdx.x & 63;
    const int wv   = threadIdx.x >> 6;
    if (lane == 0) wsum[wv] = d;
    __syncthreads();
    if (threadIdx.x == 0) {
        float s = wsum[0] + wsum[1] + wsum[2] + wsum[3];
        atomicAdd(&out[dir], s * (1.0f / (float)TOTALP));
    }
}

// ---------------------------------------------------------------------------
extern "C" void kernel_launch(void* const* d_in, const int* in_sizes, int n_in,
                              void* d_out, int out_size, void* d_ws, size_t ws_size,
                              hipStream_t stream)
{
    const float* xyz1 = (const float*)d_in[0];
    const float* xyz2 = (const float*)d_in[1];
    float* out = (float*)d_out;

    const size_t keys_bytes = (size_t)NQ * sizeof(unsigned);  // 512 KiB

    if (ws_size >= keys_bytes) {
        unsigned* keys = (unsigned*)d_ws;
        hipMemsetAsync(keys, 0xFF, keys_bytes, stream);       // keys = +inf
        hipMemsetAsync(out, 0, 2 * sizeof(float), stream);
        // 2048 blocks: dir(2) x b(16) x rb(8) x cc(8)
        chamfer_mfma<<<2048, 256, 0, stream>>>(xyz1, xyz2, keys);
        chamfer_final_atomic<<<NQ / 256, 256, 0, stream>>>(keys, out);
    } else {
        zero_out_kernel<<<1, 64, 0, stream>>>(out);
        chamfer_raw_kernel<<<512, 256, 0, stream>>>(xyz1, xyz2, out);
    }
}